// Round 18
// baseline (88.648 us; speedup 1.0000x reference)
//
#include <hip/hip_runtime.h>
#include <math.h>

#define NODES   16384
#define NGRAPH  1024
#define EDGES   245760
#define EPG     240
#define FDIM    256

#define OUT_MEAN  0
#define OUT_STD   24576
#define OUT_SCANS 49152
#define OUT_RECON 376832

typedef __attribute__((ext_vector_type(4))) short bf16x4;
typedef __attribute__((ext_vector_type(8))) short bf16x8;
typedef __attribute__((ext_vector_type(4))) float f32x4;

static __device__ __forceinline__ float lrelu02(float v){ return v > 0.f ? v : 0.2f*v; }

static __device__ __forceinline__ unsigned short f2bf(float f){
    unsigned u = __float_as_uint(f);
    u = (u + 0x7FFFu + ((u >> 16) & 1u)) >> 16;
    return (unsigned short)u;
}
static __device__ __forceinline__ float bf2f(unsigned short h){
    return __uint_as_float(((unsigned)h) << 16);
}

// ===== prep: weights + ea partials only (lidar moved into graph launch) =====
// blocks: [0,34) WTEf2 | [34,68) WTEf3 | [68,100) FT1f | 100 W1E | [101,357) ea
__global__ __launch_bounds__(256) void prep_kernel(
    const float* __restrict__ ea,
    const float* __restrict__ W2, const float* __restrict__ as2, const float* __restrict__ ad2,
    const float* __restrict__ W3, const float* __restrict__ as3, const float* __restrict__ ad3,
    const float* __restrict__ W1, const float* __restrict__ as1, const float* __restrict__ ad1,
    const float* __restrict__ F1,
    unsigned short* __restrict__ T2, unsigned short* __restrict__ T3,
    unsigned short* __restrict__ T1, float* __restrict__ W1E,
    float* __restrict__ partial)
{
    __shared__ float red[256];
    const int b = blockIdx.x;
    const int tid = threadIdx.x;

    if (b < 68) {
        const float* W   = (b < 34) ? W2 : W3;
        const float* as_ = (b < 34) ? as2 : as3;
        const float* ad_ = (b < 34) ? ad2 : ad3;
        unsigned short* T = (b < 34) ? T2 : T3;
        const int slot = ((b < 34) ? b : b - 34) * 256 + tid;
        const int nt = slot >> 9;
        const int rem = slot & 511;
        const int kk = rem >> 6;
        const int lane = rem & 63;
        const int ar = lane & 15, kgg = lane >> 4;
        const int col = nt * 16 + ar;
        unsigned short vals[8];
#pragma unroll
        for (int j = 0; j < 8; ++j) {
            const int k = kk * 32 + kgg * 4 + (j & 3) + ((j >> 2) << 4);
            float v;
            if (col < 256) v = W[k * 256 + col];
            else {
                const int j2 = col - 256, h = j2 & 7;
                const float* av = (j2 < 8) ? as_ : ad_;
                float s = 0.f;
                for (int c = 0; c < 32; ++c) s += W[k * 256 + h * 32 + c] * av[h * 32 + c];
                v = s;
            }
            vals[j] = f2bf(v);
        }
        *(bf16x8*)(T + (size_t)slot * 8) = *(const bf16x8*)vals;
        return;
    }
    if (b < 100) {
        const int slot = (b - 68) * 256 + tid;
        const int nt = slot >> 10;
        const int rem = slot & 1023;
        const int kk = rem >> 6;
        const int lane = rem & 63;
        const int o = nt * 16 + (lane & 15);
        const int kgg = lane >> 4;
        unsigned short vals[8];
#pragma unroll
        for (int j = 0; j < 8; ++j) {
            const int k = kk * 32 + kgg * 4 + (j & 3) + ((j >> 2) << 4);
            vals[j] = f2bf(F1[o * 515 + k]);
        }
        *(bf16x8*)(T1 + (size_t)slot * 8) = *(const bf16x8*)vals;
        return;
    }
    if (b == 100) {
        for (int c = tid; c < 272; c += 256) {
            for (int k = 0; k < 6; ++k) {
                float v;
                if (c < 256) v = W1[k * 256 + c];
                else {
                    const int j = c - 256, h = j & 7;
                    const float* av = (j < 8) ? as1 : ad1;
                    float s = 0.f;
                    for (int cc = 0; cc < 32; ++cc) s += W1[k * 256 + h * 32 + cc] * av[h * 32 + cc];
                    v = s;
                }
                W1E[k * 272 + c] = v;
            }
        }
        return;
    }
    {
        const int base = (b - 101) * 960;
        float s = 0.f;
        for (int i = tid; i < 960; i += 256) s += ea[base + i];
        red[tid] = s; __syncthreads();
        for (int off = 128; off > 0; off >>= 1) {
            if (tid < off) red[tid] += red[tid + off];
            __syncthreads();
        }
        if (tid == 0) partial[b - 101] = red[0];
    }
}

// ===== fused kernel: blocks [0,512) = graph-pair role (8 waves, 2 graphs);
//       blocks [512,1536) = lidar role (16 nodes, LDS aliased onto hsb) =====
__global__ __launch_bounds__(512) void graph_kernel(
    const float* __restrict__ x,   const float* __restrict__ ea,
    const float* __restrict__ partial,
    const float* __restrict__ W1E,
    const float* __restrict__ g1_We, const float* __restrict__ g1_ae,
    const float* __restrict__ g1_b,
    const unsigned short* __restrict__ WTEf2,
    const float* __restrict__ g2_We, const float* __restrict__ g2_ae,
    const float* __restrict__ g2_b,
    const unsigned short* __restrict__ WTEf3,
    const float* __restrict__ g3_We, const float* __restrict__ g3_ae,
    const float* __restrict__ g3_b,
    const unsigned short* __restrict__ FT1f,
    const float* __restrict__ fc1W, const float* __restrict__ fc1b,
    const float* __restrict__ fc2W, const float* __restrict__ fc2b,
    const float* __restrict__ w1, const float* __restrict__ b1,
    const float* __restrict__ w2, const float* __restrict__ b2,
    const float* __restrict__ wl, const float* __restrict__ bl,
    const float* __restrict__ dw1, const float* __restrict__ db1,
    const float* __restrict__ dw2, const float* __restrict__ db2,
    float* __restrict__ out)
{
    __shared__ char hsb[2][8192] __attribute__((aligned(16)));
    __shared__ float salsald[2][16][16];
    __shared__ unsigned short coefb[2][8][16][20] __attribute__((aligned(8)));
    __shared__ float sS[8];
    __shared__ float hs6[2][16][6];
    __shared__ float lash[2][8][3];
    __shared__ float hidn[16][132];
    __shared__ unsigned short gembb[2][256] __attribute__((aligned(8)));
    __shared__ float ealds[480];

    const int tid = threadIdx.x;

    // ================= lidar role (verified body; 16 nodes/block) ==========
    if (blockIdx.x >= 512) {
        float* scb = (float*)&hsb[0][0];        // [16][25]  (1600 B)
        float* plb = scb + 16 * 25;             // [16][160] (10240 B)
        float* hdb = plb + 16 * 160;            // [16][32]  (2048 B)  total 13.9KB <= hsb

        const int lane = tid & 31;
        const int nl   = tid >> 5;              // 0..15
        const int n    = (blockIdx.x - 512) * 16 + nl;

        if (lane < 20) {
            const float v = x[n * 29 + lane];
            scb[nl * 25 + lane + 2] = v;
            out[OUT_SCANS + n * 20 + lane] = v;
        } else if (lane < 25) {
            const int pads[5] = {0, 1, 22, 23, 24};
            scb[nl * 25 + pads[lane - 20]] = 0.f;
        }
        __syncthreads();

        {
            const int ic = lane & 15;
            const int hi = lane >> 4;
            float w1r[5];
#pragma unroll
            for (int k = 0; k < 5; ++k) w1r[k] = w1[ic * 5 + k];
            const float b1r = b1[ic];
#pragma unroll
            for (int q = 0; q < 5; ++q) {
                const int u  = 2 * q + hi;
                const int p0 = 2 * u;
                float a = b1r, bb = b1r;
#pragma unroll
                for (int k = 0; k < 5; ++k) {
                    a  += scb[nl * 25 + p0 + k] * w1r[k];
                    bb += scb[nl * 25 + p0 + 1 + k] * w1r[k];
                }
                plb[nl * 160 + u * 16 + ic] = fmaxf(fmaxf(a, bb), 0.f);
            }
        }
        __syncthreads();

        float macc = 0.f;
        {
            float wreg[48];
#pragma unroll
            for (int i = 0; i < 12; ++i) {
                const float4 v4 = *(const float4*)&w2[lane * 48 + i * 4];
                wreg[i * 4 + 0] = v4.x; wreg[i * 4 + 1] = v4.y;
                wreg[i * 4 + 2] = v4.z; wreg[i * 4 + 3] = v4.w;
            }
            const float b2r = b2[lane];
            float pc[3][16];
#pragma unroll
            for (int i = 0; i < 4; ++i) {
                const float4 v0 = *(const float4*)&plb[nl * 160 + 0 * 16 + i * 4];
                const float4 v1 = *(const float4*)&plb[nl * 160 + 1 * 16 + i * 4];
                pc[0][i * 4 + 0] = v0.x; pc[0][i * 4 + 1] = v0.y; pc[0][i * 4 + 2] = v0.z; pc[0][i * 4 + 3] = v0.w;
                pc[1][i * 4 + 0] = v1.x; pc[1][i * 4 + 1] = v1.y; pc[1][i * 4 + 2] = v1.z; pc[1][i * 4 + 3] = v1.w;
                pc[2][i * 4 + 0] = 0.f;  pc[2][i * 4 + 1] = 0.f;  pc[2][i * 4 + 2] = 0.f;  pc[2][i * 4 + 3] = 0.f;
            }
#pragma unroll
            for (int t = 0; t < 10; ++t) {
                const int prev = (t + 2) % 3, cur = t % 3, nxt = (t + 1) % 3;
                if (t >= 1) {
                    if (t + 1 <= 9) {
#pragma unroll
                        for (int i = 0; i < 4; ++i) {
                            const float4 v4 = *(const float4*)&plb[nl * 160 + (t + 1) * 16 + i * 4];
                            pc[nxt][i * 4 + 0] = v4.x; pc[nxt][i * 4 + 1] = v4.y;
                            pc[nxt][i * 4 + 2] = v4.z; pc[nxt][i * 4 + 3] = v4.w;
                        }
                    } else {
#pragma unroll
                        for (int ic = 0; ic < 16; ++ic) pc[nxt][ic] = 0.f;
                    }
                }
                float v = b2r;
#pragma unroll
                for (int ic = 0; ic < 16; ++ic) {
                    v += pc[prev][ic] * wreg[ic * 3 + 0]
                       + pc[cur][ic]  * wreg[ic * 3 + 1]
                       + pc[nxt][ic]  * wreg[ic * 3 + 2];
                }
                macc += fmaxf(v, 0.f);
            }
        }

        const float feat = macc * 0.1f;
        float z[5];
#pragma unroll
        for (int j = 0; j < 5; ++j) {
            float p = feat * wl[j * 32 + lane];
            p += __shfl_xor(p, 1);
            p += __shfl_xor(p, 2);
            p += __shfl_xor(p, 4);
            p += __shfl_xor(p, 8);
            p += __shfl_xor(p, 16);
            z[j] = fmaxf(bl[j] + p, 0.f);
        }
        float hv = db1[lane];
#pragma unroll
        for (int j = 0; j < 5; ++j) hv += z[j] * dw1[lane * 5 + j];
        hdb[nl * 32 + lane] = fmaxf(hv, 0.f);
        __syncthreads();

        if (lane < 20) {
            float acc = db2[lane];
#pragma unroll
            for (int k = 0; k < 32; ++k) acc += hdb[nl * 32 + k] * dw2[lane * 32 + k];
            out[OUT_RECON + n * 20 + lane] = acc;
        }
        return;
    }

    // ================= graph-pair role (unchanged, verified R17) ============
    const int g0 = blockIdx.x * 2;
    const int lane = tid & 63, w = tid >> 6;
    const int arow = lane & 15, kg = lane >> 4;

    float eamean;
    {
        float pv = partial[lane] + partial[lane + 64] + partial[lane + 128] + partial[lane + 192];
        pv += __shfl_xor(pv, 1);
        pv += __shfl_xor(pv, 2);
        pv += __shfl_xor(pv, 4);
        pv += __shfl_xor(pv, 8);
        pv += __shfl_xor(pv, 16);
        pv += __shfl_xor(pv, 32);
        eamean = pv * (1.f / (float)EDGES);
    }

    if (tid < 192) {
        const int gg = tid / 96, t = tid % 96;
        hs6[gg][t / 6][t % 6] = x[((g0 + gg) * 16 + t / 6) * 29 + 20 + t % 6];
    } else if (tid < 240) {
        const int t = tid - 192, gg = t / 24, r = t % 24;
        lash[gg][r / 3][r % 3] = x[((g0 + gg) * 16 + r / 3) * 29 + 26 + r % 3];
    } else if (tid >= 248 && tid < 256) {
        const int h = tid - 248;
        float s = 0.f;
        for (int c = 0; c < 32; ++c) s += g1_We[h * 32 + c] * g1_ae[h * 32 + c];
        sS[h] = s;
    } else if (tid >= 256) {
        const int t = tid - 256;
        ealds[t] = ea[g0 * EPG + t];
        if (t < 224) ealds[t + 256] = ea[g0 * EPG + t + 256];
    }
    __syncthreads();

    float colA[16];
    {
        const int gg = tid >> 8, ht = tid & 255;
#pragma unroll
        for (int i = 0; i < 16; ++i) colA[i] = 0.f;
#pragma unroll
        for (int k = 0; k < 6; ++k) {
            const float wa = W1E[k * 272 + ht];
#pragma unroll
            for (int i = 0; i < 16; ++i) colA[i] += hs6[gg][i][k] * wa;
        }
        if (ht < 16) {
            float colC[16];
#pragma unroll
            for (int i = 0; i < 16; ++i) colC[i] = 0.f;
#pragma unroll
            for (int k = 0; k < 6; ++k) {
                const float wc = W1E[k * 272 + 256 + ht];
#pragma unroll
                for (int i = 0; i < 16; ++i) colC[i] += hs6[gg][i][k] * wc;
            }
#pragma unroll
            for (int i = 0; i < 16; ++i) salsald[gg][i][ht] = colC[i];
        }
    }
    __syncthreads();

    if (tid < 256) {
        const int gg = tid >> 7, row = tid & 127;
        const int d = row >> 3, h = row & 7;
        const float S = sS[h];
        const float aldv = salsald[gg][d][8 + h];
        float alf[16];
        float m = -1e30f;
#pragma unroll
        for (int s = 0; s < 16; ++s) {
            float a;
            if (s == d) a = -1e30f;
            else {
                const int el = s * 15 + d - (d > s ? 1 : 0);
                a = lrelu02(salsald[gg][s][h] + aldv + ealds[gg * EPG + el] * S);
            }
            alf[s] = a;
            m = fmaxf(m, a);
        }
        float sum = 0.f;
#pragma unroll
        for (int s = 0; s < 16; ++s) { alf[s] = expf(alf[s] - m); sum += alf[s]; }
        const float r = 1.f / (sum + 1e-16f);
#pragma unroll
        for (int s = 0; s < 16; ++s) coefb[gg][h][d][s] = f2bf(alf[s] * r);
    }
    __syncthreads();

    {
        const int gg = tid >> 8, c = tid & 255;
        const int h = c >> 5;
        const float b = g1_b[c];
#pragma unroll
        for (int d = 0; d < 16; ++d) {
            float v = b;
#pragma unroll
            for (int s4 = 0; s4 < 4; ++s4) {
                const bf16x4 cv = *(const bf16x4*)((const char*)&coefb[gg][0][0][0] + h * 640 + d * 40 + s4 * 8);
                v += bf2f((unsigned short)cv[0]) * colA[s4 * 4 + 0]
                   + bf2f((unsigned short)cv[1]) * colA[s4 * 4 + 1]
                   + bf2f((unsigned short)cv[2]) * colA[s4 * 4 + 2]
                   + bf2f((unsigned short)cv[3]) * colA[s4 * 4 + 3];
            }
            *(unsigned short*)(hsb[gg] + ((d * 512 + c * 2) ^ ((d & 7) << 4))) = f2bf(fmaxf(v, 0.f));
        }
    }
    __syncthreads();

#pragma unroll 1
    for (int ly = 0; ly < 2; ++ly) {
        const unsigned short* WT = ly ? WTEf3 : WTEf2;
        const float* We_ = ly ? g3_We : g2_We;
        const float* ae_ = ly ? g3_ae : g2_ae;
        const float* bi_ = ly ? g3_b  : g2_b;

        if (tid < 8) {
            float s = 0.f;
            for (int c = 0; c < 32; ++c) s += We_[tid * 32 + c] * ae_[tid * 32 + c];
            sS[tid] = s;
        }

        f32x4 acc[3][2];
#pragma unroll
        for (int t = 0; t < 3; ++t) { acc[t][0] = (f32x4){0,0,0,0}; acc[t][1] = (f32x4){0,0,0,0}; }
        {
            const int aswz = (arow & 7) << 4;
            for (int kk = 0; kk < 8; ++kk) {
                bf16x8 afr[2];
#pragma unroll
                for (int gg = 0; gg < 2; ++gg) {
                    const int ab = arow * 512 + kk * 64 + kg * 8;
                    const bf16x4 alo = *(const bf16x4*)(hsb[gg] + (ab ^ aswz));
                    const bf16x4 ahi = *(const bf16x4*)(hsb[gg] + ((ab + 32) ^ aswz));
                    afr[gg] = (bf16x8){alo[0], alo[1], alo[2], alo[3],
                                       ahi[0], ahi[1], ahi[2], ahi[3]};
                }
#pragma unroll
                for (int t = 0; t < 2; ++t) {
                    const int nt = t * 8 + w;
                    const bf16x8 bfr = *(const bf16x8*)(WT + (size_t)((nt * 8 + kk) * 64 + lane) * 8);
                    acc[t][0] = __builtin_amdgcn_mfma_f32_16x16x32_bf16(afr[0], bfr, acc[t][0], 0, 0, 0);
                    acc[t][1] = __builtin_amdgcn_mfma_f32_16x16x32_bf16(afr[1], bfr, acc[t][1], 0, 0, 0);
                }
                if (w == 0) {
                    const bf16x8 bfr = *(const bf16x8*)(WT + (size_t)((16 * 8 + kk) * 64 + lane) * 8);
                    acc[2][0] = __builtin_amdgcn_mfma_f32_16x16x32_bf16(afr[0], bfr, acc[2][0], 0, 0, 0);
                    acc[2][1] = __builtin_amdgcn_mfma_f32_16x16x32_bf16(afr[1], bfr, acc[2][1], 0, 0, 0);
                }
            }
        }
        if (w == 0) {
#pragma unroll
            for (int gg = 0; gg < 2; ++gg)
#pragma unroll
                for (int r = 0; r < 4; ++r) salsald[gg][kg * 4 + r][arow] = acc[2][gg][r];
        }
        __syncthreads();

        if (tid < 256) {
            const int gg = tid >> 7, row = tid & 127;
            const int d = row >> 3, h = row & 7;
            const float S = sS[h];
            const float aldv = salsald[gg][d][8 + h];
            float alf[16];
            float m = -1e30f;
#pragma unroll
            for (int s = 0; s < 16; ++s) {
                float a;
                if (s == d) a = lrelu02(salsald[gg][s][h] + aldv + eamean * S);
                else {
                    const int el = s * 15 + d - (d > s ? 1 : 0);
                    a = lrelu02(salsald[gg][s][h] + aldv + ealds[gg * EPG + el] * S);
                }
                alf[s] = a;
                m = fmaxf(m, a);
            }
            float sum = 0.f;
#pragma unroll
            for (int s = 0; s < 16; ++s) { alf[s] = expf(alf[s] - m); sum += alf[s]; }
            const float r = 1.f / (sum + 1e-16f);
#pragma unroll
            for (int s = 0; s < 16; ++s) coefb[gg][h][d][s] = f2bf(alf[s] * r);
        }
        __syncthreads();

        {
#pragma unroll
            for (int t = 0; t < 2; ++t) {
                const int nt = t * 8 + w;
                const int h = nt >> 1;
                const int c2 = nt * 16 + arow;
#pragma unroll
                for (int gg = 0; gg < 2; ++gg) {
                    const bf16x4 alo = *(const bf16x4*)((const char*)&coefb[gg][0][0][0] + h * 640 + arow * 40 + kg * 8);
                    const bf16x8 afrag = (bf16x8){alo[0], alo[1], alo[2], alo[3], 0, 0, 0, 0};
                    const bf16x8 bfr = (bf16x8){
                        (short)f2bf(acc[t][gg][0]), (short)f2bf(acc[t][gg][1]),
                        (short)f2bf(acc[t][gg][2]), (short)f2bf(acc[t][gg][3]),
                        0, 0, 0, 0};
                    f32x4 hacc = __builtin_amdgcn_mfma_f32_16x16x32_bf16(
                                     afrag, bfr, (f32x4){0.f, 0.f, 0.f, 0.f}, 0, 0, 0);
                    const float b = bi_[c2];
                    float p = 0.f;
#pragma unroll
                    for (int r = 0; r < 4; ++r) {
                        const float hv = fmaxf(hacc[r] + b, 0.f);
                        p += hv;
                        const int d = kg * 4 + r;
                        *(unsigned short*)(hsb[gg] + ((d * 512 + c2 * 2) ^ ((d & 7) << 4))) = f2bf(hv);
                    }
                    if (ly == 1) {
                        p += __shfl_xor(p, 16);
                        p += __shfl_xor(p, 32);
                        if (kg == 0) gembb[gg][c2] = f2bf(p * (1.f / 16.f));
                    }
                }
            }
        }
        __syncthreads();
    }

    {
        f32x4 acc2 = (f32x4){0,0,0,0};
        const int agg = arow >> 3, alr = arow & 7;
        const int aswz = (alr & 7) << 4;
        for (int kk = 0; kk < 16; ++kk) {
            bf16x4 alo, ahi;
            if (kk < 8) {
                const int ab = alr * 512 + kk * 64 + kg * 8;
                alo = *(const bf16x4*)(hsb[agg] + (ab ^ aswz));
                ahi = *(const bf16x4*)(hsb[agg] + ((ab + 32) ^ aswz));
            } else {
                const char* gp = (const char*)&gembb[agg][0] + (kk - 8) * 64 + kg * 8;
                alo = *(const bf16x4*)(gp);
                ahi = *(const bf16x4*)(gp + 32);
            }
            const bf16x8 afrag = (bf16x8){alo[0], alo[1], alo[2], alo[3],
                                          ahi[0], ahi[1], ahi[2], ahi[3]};
            const bf16x8 bfr = *(const bf16x8*)(FT1f + (size_t)((w * 16 + kk) * 64 + lane) * 8);
            acc2 = __builtin_amdgcn_mfma_f32_16x16x32_bf16(afrag, bfr, acc2, 0, 0, 0);
        }
        {
            const int o = w * 16 + arow;
            const float wl0 = fc1W[o * 515 + 512];
            const float wl1 = fc1W[o * 515 + 513];
            const float wl2 = fc1W[o * 515 + 514];
            const float b   = fc1b[o];
#pragma unroll
            for (int r = 0; r < 4; ++r) {
                const int row = kg * 4 + r;
                const int gg = row >> 3, ag = row & 7;
                float v = acc2[r] + b
                        + lash[gg][ag][0] * wl0 + lash[gg][ag][1] * wl1 + lash[gg][ag][2] * wl2;
                hidn[row][o] = fmaxf(v, 0.f);
            }
        }
    }
    __syncthreads();

    if (tid < 96) {
        const int a = tid / 6, j = tid % 6;
        const float* wr = &fc2W[j * 128];
        float acc = fc2b[j];
#pragma unroll
        for (int k = 0; k < 128; ++k) acc += wr[k] * hidn[a][k];
        const int gg = a >> 3, ag = a & 7;
        const int base = ((g0 + gg) * 8 + ag) * 3;
        if (j < 3) {
            const float lim = (j == 2) ? 3.1415927f : 1.0f;
            out[OUT_MEAN + base + j] = tanhf(acc) * lim;
        } else {
            const float sg = 1.f / (1.f + expf(-acc));
            out[OUT_STD + base + (j - 3)] = 0.01f + sg * (0.3f - 0.01f) + 1e-5f;
        }
    }
}

extern "C" void kernel_launch(void* const* d_in, const int* in_sizes, int n_in,
                              void* d_out, int out_size, void* d_ws, size_t ws_size,
                              hipStream_t stream)
{
    const float* x     = (const float*)d_in[0];
    const float* ea    = (const float*)d_in[2];
    const float* lc_w1 = (const float*)d_in[6];
    const float* lc_b1 = (const float*)d_in[7];
    const float* lc_w2 = (const float*)d_in[8];
    const float* lc_b2 = (const float*)d_in[9];
    const float* lc_wl = (const float*)d_in[10];
    const float* lc_bl = (const float*)d_in[11];
    const float* ld_w1 = (const float*)d_in[12];
    const float* ld_b1 = (const float*)d_in[13];
    const float* ld_w2 = (const float*)d_in[14];
    const float* ld_b2 = (const float*)d_in[15];
    const float* g1_W  = (const float*)d_in[16];
    const float* g1_as = (const float*)d_in[17];
    const float* g1_ad = (const float*)d_in[18];
    const float* g1_We = (const float*)d_in[19];
    const float* g1_ae = (const float*)d_in[20];
    const float* g1_b  = (const float*)d_in[21];
    const float* g2_W  = (const float*)d_in[22];
    const float* g2_as = (const float*)d_in[23];
    const float* g2_ad = (const float*)d_in[24];
    const float* g2_We = (const float*)d_in[25];
    const float* g2_ae = (const float*)d_in[26];
    const float* g2_b  = (const float*)d_in[27];
    const float* g3_W  = (const float*)d_in[28];
    const float* g3_as = (const float*)d_in[29];
    const float* g3_ad = (const float*)d_in[30];
    const float* g3_We = (const float*)d_in[31];
    const float* g3_ae = (const float*)d_in[32];
    const float* g3_b  = (const float*)d_in[33];
    const float* fc1_W = (const float*)d_in[34];
    const float* fc1_b = (const float*)d_in[35];
    const float* fc2_W = (const float*)d_in[36];
    const float* fc2_b = (const float*)d_in[37];

    float* out = (float*)d_out;
    unsigned short* WTEf2 = (unsigned short*)d_ws;        // 8704*8 bf16
    unsigned short* WTEf3 = WTEf2 + 8704 * 8;
    unsigned short* FT1f  = WTEf3 + 8704 * 8;             // 8192*8 bf16
    float* W1E    = (float*)(FT1f + 8192 * 8);            // 6*272 f32
    float* partial = W1E + 6 * 272;                       // 256 f32

    prep_kernel<<<357, 256, 0, stream>>>(ea,
                                         g2_W, g2_as, g2_ad,
                                         g3_W, g3_as, g3_ad,
                                         g1_W, g1_as, g1_ad,
                                         fc1_W,
                                         WTEf2, WTEf3, FT1f, W1E, partial);

    graph_kernel<<<1536, 512, 0, stream>>>(x, ea, partial,
                                           W1E, g1_We, g1_ae, g1_b,
                                           WTEf2, g2_We, g2_ae, g2_b,
                                           WTEf3, g3_We, g3_ae, g3_b,
                                           FT1f, fc1_W, fc1_b, fc2_W, fc2_b,
                                           lc_w1, lc_b1, lc_w2, lc_b2, lc_wl, lc_bl,
                                           ld_w1, ld_b1, ld_w2, ld_b2,
                                           out);
}

// Round 19
// 73.352 us; speedup vs baseline: 1.2085x; 1.2085x over previous
//
#include <hip/hip_runtime.h>
#include <math.h>

#define NODES   16384
#define NGRAPH  1024
#define EDGES   245760
#define EPG     240
#define FDIM    256

#define OUT_MEAN  0
#define OUT_STD   24576
#define OUT_SCANS 49152
#define OUT_RECON 376832

typedef __attribute__((ext_vector_type(4))) short bf16x4;
typedef __attribute__((ext_vector_type(8))) short bf16x8;
typedef __attribute__((ext_vector_type(4))) float f32x4;

static __device__ __forceinline__ float lrelu02(float v){ return v > 0.f ? v : 0.2f*v; }

static __device__ __forceinline__ unsigned short f2bf(float f){
    unsigned u = __float_as_uint(f);
    u = (u + 0x7FFFu + ((u >> 16) & 1u)) >> 16;
    return (unsigned short)u;
}
static __device__ __forceinline__ float bf2f(unsigned short h){
    return __uint_as_float(((unsigned)h) << 16);
}

// ===== prep (R17-verified): weights + ea partials + lidar =====
__global__ __launch_bounds__(256) void prep_kernel(
    const float* __restrict__ x,  const float* __restrict__ ea,
    const float* __restrict__ W2, const float* __restrict__ as2, const float* __restrict__ ad2,
    const float* __restrict__ W3, const float* __restrict__ as3, const float* __restrict__ ad3,
    const float* __restrict__ W1, const float* __restrict__ as1, const float* __restrict__ ad1,
    const float* __restrict__ F1,
    const float* __restrict__ w1, const float* __restrict__ b1,
    const float* __restrict__ w2, const float* __restrict__ b2,
    const float* __restrict__ wl, const float* __restrict__ bl,
    const float* __restrict__ dw1, const float* __restrict__ db1,
    const float* __restrict__ dw2, const float* __restrict__ db2,
    unsigned short* __restrict__ T2, unsigned short* __restrict__ T3,
    unsigned short* __restrict__ T1, float* __restrict__ W1E,
    float* __restrict__ partial, float* __restrict__ out)
{
    __shared__ float red[256];
    __shared__ float sc[8][25];
    __shared__ float pooled[8][160];
    __shared__ float hid_lds[8][32];

    const int b = blockIdx.x;
    const int tid = threadIdx.x;

    if (b < 68) {
        const float* W   = (b < 34) ? W2 : W3;
        const float* as_ = (b < 34) ? as2 : as3;
        const float* ad_ = (b < 34) ? ad2 : ad3;
        unsigned short* T = (b < 34) ? T2 : T3;
        const int slot = ((b < 34) ? b : b - 34) * 256 + tid;
        const int nt = slot >> 9;
        const int rem = slot & 511;
        const int kk = rem >> 6;
        const int lane = rem & 63;
        const int ar = lane & 15, kgg = lane >> 4;
        const int col = nt * 16 + ar;
        unsigned short vals[8];
#pragma unroll
        for (int j = 0; j < 8; ++j) {
            const int k = kk * 32 + kgg * 4 + (j & 3) + ((j >> 2) << 4);
            float v;
            if (col < 256) v = W[k * 256 + col];
            else {
                const int j2 = col - 256, h = j2 & 7;
                const float* av = (j2 < 8) ? as_ : ad_;
                float s = 0.f;
                for (int c = 0; c < 32; ++c) s += W[k * 256 + h * 32 + c] * av[h * 32 + c];
                v = s;
            }
            vals[j] = f2bf(v);
        }
        *(bf16x8*)(T + (size_t)slot * 8) = *(const bf16x8*)vals;
        return;
    }
    if (b < 100) {
        const int slot = (b - 68) * 256 + tid;
        const int nt = slot >> 10;
        const int rem = slot & 1023;
        const int kk = rem >> 6;
        const int lane = rem & 63;
        const int o = nt * 16 + (lane & 15);
        const int kgg = lane >> 4;
        unsigned short vals[8];
#pragma unroll
        for (int j = 0; j < 8; ++j) {
            const int k = kk * 32 + kgg * 4 + (j & 3) + ((j >> 2) << 4);
            vals[j] = f2bf(F1[o * 515 + k]);
        }
        *(bf16x8*)(T1 + (size_t)slot * 8) = *(const bf16x8*)vals;
        return;
    }
    if (b == 100) {
        for (int c = tid; c < 272; c += 256) {
            for (int k = 0; k < 6; ++k) {
                float v;
                if (c < 256) v = W1[k * 256 + c];
                else {
                    const int j = c - 256, h = j & 7;
                    const float* av = (j < 8) ? as1 : ad1;
                    float s = 0.f;
                    for (int cc = 0; cc < 32; ++cc) s += W1[k * 256 + h * 32 + cc] * av[h * 32 + cc];
                    v = s;
                }
                W1E[k * 272 + c] = v;
            }
        }
        return;
    }
    if (b < 357) {
        const int base = (b - 101) * 960;
        float s = 0.f;
        for (int i = tid; i < 960; i += 256) s += ea[base + i];
        red[tid] = s; __syncthreads();
        for (int off = 128; off > 0; off >>= 1) {
            if (tid < off) red[tid] += red[tid + off];
            __syncthreads();
        }
        if (tid == 0) partial[b - 101] = red[0];
        return;
    }

    // ---- lidar (verified body) ----
    const int lane = tid & 31;
    const int nl   = tid >> 5;
    const int n    = (b - 357) * 8 + nl;

    if (lane < 20) {
        const float v = x[n * 29 + lane];
        sc[nl][lane + 2] = v;
        out[OUT_SCANS + n * 20 + lane] = v;
    } else if (lane < 25) {
        const int pads[5] = {0, 1, 22, 23, 24};
        sc[nl][pads[lane - 20]] = 0.f;
    }
    __syncthreads();

    {
        const int ic = lane & 15;
        const int hi = lane >> 4;
        float w1r[5];
#pragma unroll
        for (int k = 0; k < 5; ++k) w1r[k] = w1[ic * 5 + k];
        const float b1r = b1[ic];
#pragma unroll
        for (int q = 0; q < 5; ++q) {
            const int u  = 2 * q + hi;
            const int p0 = 2 * u;
            float a = b1r, bb = b1r;
#pragma unroll
            for (int k = 0; k < 5; ++k) {
                a  += sc[nl][p0 + k] * w1r[k];
                bb += sc[nl][p0 + 1 + k] * w1r[k];
            }
            pooled[nl][u * 16 + ic] = fmaxf(fmaxf(a, bb), 0.f);
        }
    }
    __syncthreads();

    float macc = 0.f;
    {
        float wreg[48];
#pragma unroll
        for (int i = 0; i < 12; ++i) {
            const float4 v4 = *(const float4*)&w2[lane * 48 + i * 4];
            wreg[i * 4 + 0] = v4.x; wreg[i * 4 + 1] = v4.y;
            wreg[i * 4 + 2] = v4.z; wreg[i * 4 + 3] = v4.w;
        }
        const float b2r = b2[lane];
        float pc[3][16];
#pragma unroll
        for (int i = 0; i < 4; ++i) {
            const float4 v0 = *(const float4*)&pooled[nl][0 * 16 + i * 4];
            const float4 v1 = *(const float4*)&pooled[nl][1 * 16 + i * 4];
            pc[0][i * 4 + 0] = v0.x; pc[0][i * 4 + 1] = v0.y; pc[0][i * 4 + 2] = v0.z; pc[0][i * 4 + 3] = v0.w;
            pc[1][i * 4 + 0] = v1.x; pc[1][i * 4 + 1] = v1.y; pc[1][i * 4 + 2] = v1.z; pc[1][i * 4 + 3] = v1.w;
            pc[2][i * 4 + 0] = 0.f;  pc[2][i * 4 + 1] = 0.f;  pc[2][i * 4 + 2] = 0.f;  pc[2][i * 4 + 3] = 0.f;
        }
#pragma unroll
        for (int t = 0; t < 10; ++t) {
            const int prev = (t + 2) % 3, cur = t % 3, nxt = (t + 1) % 3;
            if (t >= 1) {
                if (t + 1 <= 9) {
#pragma unroll
                    for (int i = 0; i < 4; ++i) {
                        const float4 v4 = *(const float4*)&pooled[nl][(t + 1) * 16 + i * 4];
                        pc[nxt][i * 4 + 0] = v4.x; pc[nxt][i * 4 + 1] = v4.y;
                        pc[nxt][i * 4 + 2] = v4.z; pc[nxt][i * 4 + 3] = v4.w;
                    }
                } else {
#pragma unroll
                    for (int ic = 0; ic < 16; ++ic) pc[nxt][ic] = 0.f;
                }
            }
            float v = b2r;
#pragma unroll
            for (int ic = 0; ic < 16; ++ic) {
                v += pc[prev][ic] * wreg[ic * 3 + 0]
                   + pc[cur][ic]  * wreg[ic * 3 + 1]
                   + pc[nxt][ic]  * wreg[ic * 3 + 2];
            }
            macc += fmaxf(v, 0.f);
        }
    }

    const float feat = macc * 0.1f;
    float z[5];
#pragma unroll
    for (int j = 0; j < 5; ++j) {
        float p = feat * wl[j * 32 + lane];
        p += __shfl_xor(p, 1);
        p += __shfl_xor(p, 2);
        p += __shfl_xor(p, 4);
        p += __shfl_xor(p, 8);
        p += __shfl_xor(p, 16);
        z[j] = fmaxf(bl[j] + p, 0.f);
    }
    float hv = db1[lane];
#pragma unroll
    for (int j = 0; j < 5; ++j) hv += z[j] * dw1[lane * 5 + j];
    hid_lds[nl][lane] = fmaxf(hv, 0.f);
    __syncthreads();

    if (lane < 20) {
        float acc = db2[lane];
#pragma unroll
        for (int k = 0; k < 32; ++k) acc += hid_lds[nl][k] * dw2[lane * 32 + k];
        out[OUT_RECON + n * 20 + lane] = acc;
    }
}

// ===== per-graph-pair kernel (R17-verified): 512 blocks x 512 threads =====
__global__ __launch_bounds__(512) void graph_kernel(
    const float* __restrict__ x,   const float* __restrict__ ea,
    const float* __restrict__ partial,
    const float* __restrict__ W1E,
    const float* __restrict__ g1_We, const float* __restrict__ g1_ae,
    const float* __restrict__ g1_b,
    const unsigned short* __restrict__ WTEf2,
    const float* __restrict__ g2_We, const float* __restrict__ g2_ae,
    const float* __restrict__ g2_b,
    const unsigned short* __restrict__ WTEf3,
    const float* __restrict__ g3_We, const float* __restrict__ g3_ae,
    const float* __restrict__ g3_b,
    const unsigned short* __restrict__ FT1f,
    const float* __restrict__ fc1W, const float* __restrict__ fc1b,
    const float* __restrict__ fc2W, const float* __restrict__ fc2b,
    float* __restrict__ out)
{
    __shared__ char hsb[2][8192] __attribute__((aligned(16)));
    __shared__ float salsald[2][16][16];
    __shared__ unsigned short coefb[2][8][16][20] __attribute__((aligned(8)));
    __shared__ float sS[8];
    __shared__ float hs6[2][16][6];
    __shared__ float lash[2][8][3];
    __shared__ float hidn[16][132];
    __shared__ unsigned short gembb[2][256] __attribute__((aligned(8)));
    __shared__ float ealds[480];

    const int tid = threadIdx.x;
    const int g0 = blockIdx.x * 2;
    const int lane = tid & 63, w = tid >> 6;
    const int arow = lane & 15, kg = lane >> 4;

    float eamean;
    {
        float pv = partial[lane] + partial[lane + 64] + partial[lane + 128] + partial[lane + 192];
        pv += __shfl_xor(pv, 1);
        pv += __shfl_xor(pv, 2);
        pv += __shfl_xor(pv, 4);
        pv += __shfl_xor(pv, 8);
        pv += __shfl_xor(pv, 16);
        pv += __shfl_xor(pv, 32);
        eamean = pv * (1.f / (float)EDGES);
    }

    if (tid < 192) {
        const int gg = tid / 96, t = tid % 96;
        hs6[gg][t / 6][t % 6] = x[((g0 + gg) * 16 + t / 6) * 29 + 20 + t % 6];
    } else if (tid < 240) {
        const int t = tid - 192, gg = t / 24, r = t % 24;
        lash[gg][r / 3][r % 3] = x[((g0 + gg) * 16 + r / 3) * 29 + 26 + r % 3];
    } else if (tid >= 248 && tid < 256) {
        const int h = tid - 248;
        float s = 0.f;
        for (int c = 0; c < 32; ++c) s += g1_We[h * 32 + c] * g1_ae[h * 32 + c];
        sS[h] = s;
    } else if (tid >= 256) {
        const int t = tid - 256;
        ealds[t] = ea[g0 * EPG + t];
        if (t < 224) ealds[t + 256] = ea[g0 * EPG + t + 256];
    }
    __syncthreads();

    float colA[16];
    {
        const int gg = tid >> 8, ht = tid & 255;
#pragma unroll
        for (int i = 0; i < 16; ++i) colA[i] = 0.f;
#pragma unroll
        for (int k = 0; k < 6; ++k) {
            const float wa = W1E[k * 272 + ht];
#pragma unroll
            for (int i = 0; i < 16; ++i) colA[i] += hs6[gg][i][k] * wa;
        }
        if (ht < 16) {
            float colC[16];
#pragma unroll
            for (int i = 0; i < 16; ++i) colC[i] = 0.f;
#pragma unroll
            for (int k = 0; k < 6; ++k) {
                const float wc = W1E[k * 272 + 256 + ht];
#pragma unroll
                for (int i = 0; i < 16; ++i) colC[i] += hs6[gg][i][k] * wc;
            }
#pragma unroll
            for (int i = 0; i < 16; ++i) salsald[gg][i][ht] = colC[i];
        }
    }
    __syncthreads();

    if (tid < 256) {
        const int gg = tid >> 7, row = tid & 127;
        const int d = row >> 3, h = row & 7;
        const float S = sS[h];
        const float aldv = salsald[gg][d][8 + h];
        float alf[16];
        float m = -1e30f;
#pragma unroll
        for (int s = 0; s < 16; ++s) {
            float a;
            if (s == d) a = -1e30f;
            else {
                const int el = s * 15 + d - (d > s ? 1 : 0);
                a = lrelu02(salsald[gg][s][h] + aldv + ealds[gg * EPG + el] * S);
            }
            alf[s] = a;
            m = fmaxf(m, a);
        }
        float sum = 0.f;
#pragma unroll
        for (int s = 0; s < 16; ++s) { alf[s] = expf(alf[s] - m); sum += alf[s]; }
        const float r = 1.f / (sum + 1e-16f);
#pragma unroll
        for (int s = 0; s < 16; ++s) coefb[gg][h][d][s] = f2bf(alf[s] * r);
    }
    __syncthreads();

    {
        const int gg = tid >> 8, c = tid & 255;
        const int h = c >> 5;
        const float b = g1_b[c];
#pragma unroll
        for (int d = 0; d < 16; ++d) {
            float v = b;
#pragma unroll
            for (int s4 = 0; s4 < 4; ++s4) {
                const bf16x4 cv = *(const bf16x4*)((const char*)&coefb[gg][0][0][0] + h * 640 + d * 40 + s4 * 8);
                v += bf2f((unsigned short)cv[0]) * colA[s4 * 4 + 0]
                   + bf2f((unsigned short)cv[1]) * colA[s4 * 4 + 1]
                   + bf2f((unsigned short)cv[2]) * colA[s4 * 4 + 2]
                   + bf2f((unsigned short)cv[3]) * colA[s4 * 4 + 3];
            }
            *(unsigned short*)(hsb[gg] + ((d * 512 + c * 2) ^ ((d & 7) << 4))) = f2bf(fmaxf(v, 0.f));
        }
    }
    __syncthreads();

#pragma unroll 1
    for (int ly = 0; ly < 2; ++ly) {
        const unsigned short* WT = ly ? WTEf3 : WTEf2;
        const float* We_ = ly ? g3_We : g2_We;
        const float* ae_ = ly ? g3_ae : g2_ae;
        const float* bi_ = ly ? g3_b  : g2_b;

        if (tid < 8) {
            float s = 0.f;
            for (int c = 0; c < 32; ++c) s += We_[tid * 32 + c] * ae_[tid * 32 + c];
            sS[tid] = s;
        }

        f32x4 acc[3][2];
#pragma unroll
        for (int t = 0; t < 3; ++t) { acc[t][0] = (f32x4){0,0,0,0}; acc[t][1] = (f32x4){0,0,0,0}; }
        {
            const int aswz = (arow & 7) << 4;
            for (int kk = 0; kk < 8; ++kk) {
                bf16x8 afr[2];
#pragma unroll
                for (int gg = 0; gg < 2; ++gg) {
                    const int ab = arow * 512 + kk * 64 + kg * 8;
                    const bf16x4 alo = *(const bf16x4*)(hsb[gg] + (ab ^ aswz));
                    const bf16x4 ahi = *(const bf16x4*)(hsb[gg] + ((ab + 32) ^ aswz));
                    afr[gg] = (bf16x8){alo[0], alo[1], alo[2], alo[3],
                                       ahi[0], ahi[1], ahi[2], ahi[3]};
                }
#pragma unroll
                for (int t = 0; t < 2; ++t) {
                    const int nt = t * 8 + w;
                    const bf16x8 bfr = *(const bf16x8*)(WT + (size_t)((nt * 8 + kk) * 64 + lane) * 8);
                    acc[t][0] = __builtin_amdgcn_mfma_f32_16x16x32_bf16(afr[0], bfr, acc[t][0], 0, 0, 0);
                    acc[t][1] = __builtin_amdgcn_mfma_f32_16x16x32_bf16(afr[1], bfr, acc[t][1], 0, 0, 0);
                }
                if (w == 0) {
                    const bf16x8 bfr = *(const bf16x8*)(WT + (size_t)((16 * 8 + kk) * 64 + lane) * 8);
                    acc[2][0] = __builtin_amdgcn_mfma_f32_16x16x32_bf16(afr[0], bfr, acc[2][0], 0, 0, 0);
                    acc[2][1] = __builtin_amdgcn_mfma_f32_16x16x32_bf16(afr[1], bfr, acc[2][1], 0, 0, 0);
                }
            }
        }
        if (w == 0) {
#pragma unroll
            for (int gg = 0; gg < 2; ++gg)
#pragma unroll
                for (int r = 0; r < 4; ++r) salsald[gg][kg * 4 + r][arow] = acc[2][gg][r];
        }
        __syncthreads();

        if (tid < 256) {
            const int gg = tid >> 7, row = tid & 127;
            const int d = row >> 3, h = row & 7;
            const float S = sS[h];
            const float aldv = salsald[gg][d][8 + h];
            float alf[16];
            float m = -1e30f;
#pragma unroll
            for (int s = 0; s < 16; ++s) {
                float a;
                if (s == d) a = lrelu02(salsald[gg][s][h] + aldv + eamean * S);
                else {
                    const int el = s * 15 + d - (d > s ? 1 : 0);
                    a = lrelu02(salsald[gg][s][h] + aldv + ealds[gg * EPG + el] * S);
                }
                alf[s] = a;
                m = fmaxf(m, a);
            }
            float sum = 0.f;
#pragma unroll
            for (int s = 0; s < 16; ++s) { alf[s] = expf(alf[s] - m); sum += alf[s]; }
            const float r = 1.f / (sum + 1e-16f);
#pragma unroll
            for (int s = 0; s < 16; ++s) coefb[gg][h][d][s] = f2bf(alf[s] * r);
        }
        __syncthreads();

        {
#pragma unroll
            for (int t = 0; t < 2; ++t) {
                const int nt = t * 8 + w;
                const int h = nt >> 1;
                const int c2 = nt * 16 + arow;
#pragma unroll
                for (int gg = 0; gg < 2; ++gg) {
                    const bf16x4 alo = *(const bf16x4*)((const char*)&coefb[gg][0][0][0] + h * 640 + arow * 40 + kg * 8);
                    const bf16x8 afrag = (bf16x8){alo[0], alo[1], alo[2], alo[3], 0, 0, 0, 0};
                    const bf16x8 bfr = (bf16x8){
                        (short)f2bf(acc[t][gg][0]), (short)f2bf(acc[t][gg][1]),
                        (short)f2bf(acc[t][gg][2]), (short)f2bf(acc[t][gg][3]),
                        0, 0, 0, 0};
                    f32x4 hacc = __builtin_amdgcn_mfma_f32_16x16x32_bf16(
                                     afrag, bfr, (f32x4){0.f, 0.f, 0.f, 0.f}, 0, 0, 0);
                    const float b = bi_[c2];
                    float p = 0.f;
#pragma unroll
                    for (int r = 0; r < 4; ++r) {
                        const float hv = fmaxf(hacc[r] + b, 0.f);
                        p += hv;
                        const int d = kg * 4 + r;
                        *(unsigned short*)(hsb[gg] + ((d * 512 + c2 * 2) ^ ((d & 7) << 4))) = f2bf(hv);
                    }
                    if (ly == 1) {
                        p += __shfl_xor(p, 16);
                        p += __shfl_xor(p, 32);
                        if (kg == 0) gembb[gg][c2] = f2bf(p * (1.f / 16.f));
                    }
                }
            }
        }
        __syncthreads();
    }

    {
        f32x4 acc2 = (f32x4){0,0,0,0};
        const int agg = arow >> 3, alr = arow & 7;
        const int aswz = (alr & 7) << 4;
        for (int kk = 0; kk < 16; ++kk) {
            bf16x4 alo, ahi;
            if (kk < 8) {
                const int ab = alr * 512 + kk * 64 + kg * 8;
                alo = *(const bf16x4*)(hsb[agg] + (ab ^ aswz));
                ahi = *(const bf16x4*)(hsb[agg] + ((ab + 32) ^ aswz));
            } else {
                const char* gp = (const char*)&gembb[agg][0] + (kk - 8) * 64 + kg * 8;
                alo = *(const bf16x4*)(gp);
                ahi = *(const bf16x4*)(gp + 32);
            }
            const bf16x8 afrag = (bf16x8){alo[0], alo[1], alo[2], alo[3],
                                          ahi[0], ahi[1], ahi[2], ahi[3]};
            const bf16x8 bfr = *(const bf16x8*)(FT1f + (size_t)((w * 16 + kk) * 64 + lane) * 8);
            acc2 = __builtin_amdgcn_mfma_f32_16x16x32_bf16(afrag, bfr, acc2, 0, 0, 0);
        }
        {
            const int o = w * 16 + arow;
            const float wl0 = fc1W[o * 515 + 512];
            const float wl1 = fc1W[o * 515 + 513];
            const float wl2 = fc1W[o * 515 + 514];
            const float b   = fc1b[o];
#pragma unroll
            for (int r = 0; r < 4; ++r) {
                const int row = kg * 4 + r;
                const int gg = row >> 3, ag = row & 7;
                float v = acc2[r] + b
                        + lash[gg][ag][0] * wl0 + lash[gg][ag][1] * wl1 + lash[gg][ag][2] * wl2;
                hidn[row][o] = fmaxf(v, 0.f);
            }
        }
    }
    __syncthreads();

    if (tid < 96) {
        const int a = tid / 6, j = tid % 6;
        const float* wr = &fc2W[j * 128];
        float acc = fc2b[j];
#pragma unroll
        for (int k = 0; k < 128; ++k) acc += wr[k] * hidn[a][k];
        const int gg = a >> 3, ag = a & 7;
        const int base = ((g0 + gg) * 8 + ag) * 3;
        if (j < 3) {
            const float lim = (j == 2) ? 3.1415927f : 1.0f;
            out[OUT_MEAN + base + j] = tanhf(acc) * lim;
        } else {
            const float sg = 1.f / (1.f + expf(-acc));
            out[OUT_STD + base + (j - 3)] = 0.01f + sg * (0.3f - 0.01f) + 1e-5f;
        }
    }
}

extern "C" void kernel_launch(void* const* d_in, const int* in_sizes, int n_in,
                              void* d_out, int out_size, void* d_ws, size_t ws_size,
                              hipStream_t stream)
{
    const float* x     = (const float*)d_in[0];
    const float* ea    = (const float*)d_in[2];
    const float* lc_w1 = (const float*)d_in[6];
    const float* lc_b1 = (const float*)d_in[7];
    const float* lc_w2 = (const float*)d_in[8];
    const float* lc_b2 = (const float*)d_in[9];
    const float* lc_wl = (const float*)d_in[10];
    const float* lc_bl = (const float*)d_in[11];
    const float* ld_w1 = (const float*)d_in[12];
    const float* ld_b1 = (const float*)d_in[13];
    const float* ld_w2 = (const float*)d_in[14];
    const float* ld_b2 = (const float*)d_in[15];
    const float* g1_W  = (const float*)d_in[16];
    const float* g1_as = (const float*)d_in[17];
    const float* g1_ad = (const float*)d_in[18];
    const float* g1_We = (const float*)d_in[19];
    const float* g1_ae = (const float*)d_in[20];
    const float* g1_b  = (const float*)d_in[21];
    const float* g2_W  = (const float*)d_in[22];
    const float* g2_as = (const float*)d_in[23];
    const float* g2_ad = (const float*)d_in[24];
    const float* g2_We = (const float*)d_in[25];
    const float* g2_ae = (const float*)d_in[26];
    const float* g2_b  = (const float*)d_in[27];
    const float* g3_W  = (const float*)d_in[28];
    const float* g3_as = (const float*)d_in[29];
    const float* g3_ad = (const float*)d_in[30];
    const float* g3_We = (const float*)d_in[31];
    const float* g3_ae = (const float*)d_in[32];
    const float* g3_b  = (const float*)d_in[33];
    const float* fc1_W = (const float*)d_in[34];
    const float* fc1_b = (const float*)d_in[35];
    const float* fc2_W = (const float*)d_in[36];
    const float* fc2_b = (const float*)d_in[37];

    float* out = (float*)d_out;
    unsigned short* WTEf2 = (unsigned short*)d_ws;        // 8704*8 bf16
    unsigned short* WTEf3 = WTEf2 + 8704 * 8;
    unsigned short* FT1f  = WTEf3 + 8704 * 8;             // 8192*8 bf16
    float* W1E    = (float*)(FT1f + 8192 * 8);            // 6*272 f32
    float* partial = W1E + 6 * 272;                       // 256 f32

    prep_kernel<<<2405, 256, 0, stream>>>(x, ea,
                                          g2_W, g2_as, g2_ad,
                                          g3_W, g3_as, g3_ad,
                                          g1_W, g1_as, g1_ad,
                                          fc1_W,
                                          lc_w1, lc_b1, lc_w2, lc_b2, lc_wl, lc_bl,
                                          ld_w1, ld_b1, ld_w2, ld_b2,
                                          WTEf2, WTEf3, FT1f, W1E, partial, out);

    graph_kernel<<<512, 512, 0, stream>>>(x, ea, partial,
                                          W1E, g1_We, g1_ae, g1_b,
                                          WTEf2, g2_We, g2_ae, g2_b,
                                          WTEf3, g3_We, g3_ae, g3_b,
                                          FT1f, fc1_W, fc1_b, fc2_W, fc2_b, out);
}